// Round 20
// baseline (75.986 us; speedup 1.0000x reference)
//
#include <hip/hip_runtime.h>
#include <hip/hip_bf16.h>

#define NROW 8192
#define NDIM 128
#define CTILE 32   // cols per tile (8KB LDS) -> L[2]=16KB/block -> up to 10 blocks/CU
#define CCHUNK 8   // tiles per block -> 256 cols/block; grid (32,64)=2048 blocks (8/CU)
#define RBLK 128   // rows per block (4 waves x 32 rows)
#define CAP 64     // max rows per class (mean 16, P(>64) ~ 1e-20, stores guarded)
#define NCLS 512

typedef __attribute__((ext_vector_type(8))) short short8;
typedef __attribute__((ext_vector_type(4))) float f32x4;
typedef __attribute__((address_space(1))) const unsigned int guint;
typedef __attribute__((address_space(3))) unsigned int luint;

__device__ __forceinline__ unsigned f2u_mono(float f) {
  unsigned u = __float_as_uint(f);
  return (u & 0x80000000u) ? ~u : (u | 0x80000000u);
}
__device__ __forceinline__ float u2f_mono(unsigned u) {
  return __uint_as_float((u & 0x80000000u) ? (u ^ 0x80000000u) : ~u);
}
__device__ __forceinline__ unsigned short f2bf(float f) {  // RTN fp32->bf16
  unsigned u = __float_as_uint(f);
  u += 0x7fffu + ((u >> 16) & 1u);
  return (unsigned short)(u >> 16);
}

// Fused: bf16 convert + class-list build + zero-init of k_neg's atomic buffers
// (stream order guarantees they're zeroed before k_neg runs).
__global__ __launch_bounds__(256) void k_convert(const float* __restrict__ e,
                                                 unsigned short* __restrict__ h,
                                                 const int* __restrict__ labels,
                                                 unsigned* __restrict__ cls_cnt,
                                                 int* __restrict__ cls_list,
                                                 unsigned* __restrict__ nmaxu,
                                                 float* __restrict__ anb,
                                                 float* __restrict__ hnb) {
  const int gid = blockIdx.x * 256 + threadIdx.x;
  if (gid < NROW) {
    const int c = labels[gid];
    const unsigned idx = atomicAdd(&cls_cnt[c], 1u);
    if (idx < CAP) cls_list[c * CAP + idx] = gid;
    nmaxu[gid] = 0u;   // mono sentinel: decodes to NaN -> compares false
    anb[gid] = 0.f;
    hnb[gid] = 0.f;
  }
  int i = gid * 8;
  float4 f0 = *reinterpret_cast<const float4*>(e + i);
  float4 f1 = *reinterpret_cast<const float4*>(e + i + 4);
  ushort4 a, b;
  a.x = f2bf(f0.x); a.y = f2bf(f0.y); a.z = f2bf(f0.z); a.w = f2bf(f0.w);
  b.x = f2bf(f1.x); b.y = f2bf(f1.y); b.z = f2bf(f1.z); b.w = f2bf(f1.w);
  *reinterpret_cast<ushort4*>(h + i) = a;
  *reinterpret_cast<ushort4*>(h + i + 4) = b;
}

// Positives: one block per class. Stage class rows (fp32) into LDS, thread
// (i,j)=(t>>4,t&15) computes one pair dot (256 pairs in flight). Diagonal
// stored as +INF (min-neutral, exp(-inf)=0, hard-compare false). Writes
// pmin/ap (no atomics) and caches all dots for the final pass.
__global__ __launch_bounds__(256) void k_pos1(
    const float* __restrict__ emb, const unsigned* __restrict__ cls_cnt,
    const int* __restrict__ cls_list, float* __restrict__ pmin,
    float* __restrict__ apb, float* __restrict__ pcache) {
  __shared__ float Le[CAP][NDIM + 1];  // +1 pad: bank (j+d)%32 -> conflict-free
  __shared__ int rows_s[CAP];
  const int c = blockIdx.x;
  const int t = threadIdx.x;
  const int cnt = (int)min(cls_cnt[c], (unsigned)CAP);
  if (cnt == 0) return;  // block-uniform
  if (t < cnt) rows_s[t] = cls_list[c * CAP + t];
  __syncthreads();
  for (int idx = t; idx < cnt * NDIM; idx += 256) {
    const int k = idx >> 7, d = idx & 127;
    Le[k][d] = emb[(size_t)rows_s[k] * NDIM + d];
  }
  __syncthreads();

  const int il = t >> 4, jl = t & 15;
  for (int ib = 0; ib < cnt; ib += 16) {
    const int i = ib + il;
    float pm = INFINITY, apv = 0.f;
    for (int jb = 0; jb < cnt; jb += 16) {
      const int j = jb + jl;
      float p = INFINITY;
      if (i < cnt && j < cnt) {
        if (i != j) {
          float s = 0.f;
#pragma unroll 8
          for (int d = 0; d < NDIM; ++d) s = fmaf(Le[i][d], Le[j][d], s);
          p = s;
        }
        pcache[(size_t)rows_s[i] * CAP + j] = p;  // +INF on diagonal
        if (i != j) {
          pm = fminf(pm, p);
          apv += exp2f(fmaf(p, -2.885390082f, 1.442695041f));  // exp(-2(p-.5))
        }
      }
    }
    pm = fminf(pm, __shfl_xor(pm, 1)); pm = fminf(pm, __shfl_xor(pm, 2));
    pm = fminf(pm, __shfl_xor(pm, 4)); pm = fminf(pm, __shfl_xor(pm, 8));
    apv += __shfl_xor(apv, 1); apv += __shfl_xor(apv, 2);
    apv += __shfl_xor(apv, 4); apv += __shfl_xor(apv, 8);
    if (jl == 0 && i < cnt) {
      pmin[rows_s[i]] = pm;   // +INF if class has a single row
      apb[rows_s[i]] = apv;
    }
  }
}

// DMA one 32x128 bf16 col-tile into LDS. Dest LINEAR (global_load_lds writes
// wave-uniform base + lane*16); XOR swizzle applied to the GLOBAL source chunk.
__device__ __forceinline__ void stage_tile(const unsigned short* __restrict__ eh,
                                           int colBase, int t,
                                           unsigned short* __restrict__ Lbuf) {
#pragma unroll
  for (int it = 0; it < 2; ++it) {
    const int idx = it * 256 + t;
    const int r = idx >> 4;             // 0..31
    const int c = idx & 15;
    const int q = c ^ (r & 15);
    const unsigned short* src = eh + (size_t)(colBase + r) * NDIM + q * 8;
    unsigned short* dst = Lbuf + r * NDIM + c * 8;
    __builtin_amdgcn_global_load_lds((guint*)src, (luint*)dst, 16, 0, 0);
  }
}

// kk=0 uses a hoisted zero f32x4 as the C operand -> no per-tile acc zeroing.
__device__ __forceinline__ void mfma_from_lds(const unsigned short* __restrict__ Lbuf,
                                              const short8 (&bv)[4][2],
                                              const f32x4& Z,
                                              int g, int l15,
                                              f32x4 (&acc)[2][2]) {
#pragma unroll
  for (int kk = 0; kk < 4; ++kk) {
    short8 av[2];
#pragma unroll
    for (int m = 0; m < 2; ++m) {
      const int R = m * 16 + l15;
      const int pc = (kk * 4 + g) ^ l15;
      av[m] = *reinterpret_cast<const short8*>(Lbuf + R * NDIM + pc * 8);
    }
#pragma unroll
    for (int m = 0; m < 2; ++m)
#pragma unroll
      for (int n = 0; n < 2; ++n)
        acc[m][n] = __builtin_amdgcn_mfma_f32_16x16x32_bf16(
            av[m], bv[kk][n], (kk == 0) ? Z : acc[m][n], 0, 0, 0);
  }
}

// Negatives pass: the ONE full GEMM. x-trick epilogue: x = eq ? -inf : s feeds
// nmax (neutral), exp (0), and hn compare (false). 16KB LDS/block -> target
// 8 blocks/CU resident (vs 4 at CTILE=64) for 2x latency hiding.
__global__ __launch_bounds__(256, 4) void k_neg(
    const unsigned short* __restrict__ eh, const int* __restrict__ labels,
    const float* __restrict__ pmin, unsigned* __restrict__ nmaxu,
    float* __restrict__ anb, float* __restrict__ hnb) {
  __shared__ unsigned short L[2][CTILE * NDIM];  // 2 x 8KB

  const int t = threadIdx.x;
  const int lane = t & 63;
  const int wid = t >> 6;   // 4 waves x 32 rows
  const int g = lane >> 4;
  const int l15 = lane & 15;
  const int rowBase = blockIdx.y * RBLK;
  const int col0 = blockIdx.x * CCHUNK * CTILE;

  stage_tile(eh, col0, t, L[0]);  // prologue DMA for tile 0

  short8 bv[4][2];
  int lr[2];
  float thrn[2];
#pragma unroll
  for (int n = 0; n < 2; ++n) {
    const int grow = rowBase + wid * 32 + n * 16 + l15;
    lr[n] = labels[grow];
    thrn[n] = pmin[grow] - 0.1f;  // +INF if no positives -> x>thrn false -> hn=0
#pragma unroll
    for (int kk = 0; kk < 4; ++kk)
      bv[kk][n] = *reinterpret_cast<const short8*>(eh + (size_t)grow * NDIM + kk * 32 + g * 8);
  }

  float nmaxA[2] = {-INFINITY, -INFINITY};
  float anA[2] = {0.f, 0.f}, hnA[2] = {0.f, 0.f};
  const f32x4 Z = {0.f, 0.f, 0.f, 0.f};

  asm volatile("s_waitcnt vmcnt(0)");
  __syncthreads();

  f32x4 acc[2][2];
  int cur = 0;
  for (int tt = 0; tt < CCHUNK; ++tt) {
    const int colBase = col0 + tt * CTILE;
    if (tt + 1 < CCHUNK) stage_tile(eh, colBase + CTILE, t, L[cur ^ 1]);  // DMA next
    int4 lcv[2];  // issued before MFMA so L2 latency hides under it
#pragma unroll
    for (int m = 0; m < 2; ++m)
      lcv[m] = *reinterpret_cast<const int4*>(labels + colBase + m * 16 + g * 4);
    mfma_from_lds(L[cur], bv, Z, g, l15, acc);
#pragma unroll
    for (int n = 0; n < 2; ++n) {
#pragma unroll
      for (int m = 0; m < 2; ++m) {
#pragma unroll
        for (int r = 0; r < 4; ++r) {
          const float s = acc[m][n][r];
          const int lc = (r == 0) ? lcv[m].x : (r == 1) ? lcv[m].y
                        : (r == 2) ? lcv[m].z : lcv[m].w;
          const float x = (lr[n] == lc) ? -INFINITY : s;   // excl. pos + diag
          nmaxA[n] = fmaxf(nmaxA[n], x);
          const float e = exp2f(fmaf(x, 72.13475205f, -36.06737602f));  // exp(50(x-.5))
          anA[n] += e;                                      // 0 when excluded
          hnA[n] += (x > thrn[n]) ? e : 0.f;                // false when excluded
        }
      }
    }
    asm volatile("s_waitcnt vmcnt(0)");  // next-tile DMA landed (covered by compute)
    __syncthreads();
    cur ^= 1;
  }

  // block-end combine: butterfly across the 4 g-groups, then one atomic per lane
#pragma unroll
  for (int n = 0; n < 2; ++n) {
    const int grow = rowBase + wid * 32 + n * 16 + l15;
    float nm = nmaxA[n], a0 = anA[n], a1 = hnA[n];
    nm = fmaxf(nm, __shfl_xor(nm, 16)); nm = fmaxf(nm, __shfl_xor(nm, 32));
    a0 += __shfl_xor(a0, 16); a0 += __shfl_xor(a0, 32);
    a1 += __shfl_xor(a1, 16); a1 += __shfl_xor(a1, 32);
    if (g == 0 && nm > -INFINITY) atomicMax(&nmaxu[grow], f2u_mono(nm));
    if (g == 1 && a0 > 0.f) atomicAdd(&anb[grow], a0);
    if (g == 2 && a1 > 0.f) atomicAdd(&hnb[grow], a1);
  }
}

// Fused hard-pos + final reduction: 32 blocks, thread per row. hp from cached
// pos dots; block partials via atomicAdd; last-done block writes the mean.
__global__ __launch_bounds__(256) void k_final(
    const int* __restrict__ labels, const unsigned* __restrict__ cls_cnt,
    const unsigned* __restrict__ nmaxu, const float* __restrict__ pcache,
    const float* __restrict__ apb, const float* __restrict__ anb,
    const float* __restrict__ hnb, float* __restrict__ partial,
    unsigned* __restrict__ done, float* __restrict__ out) {
  const int t = threadIdx.x;
  const int row = blockIdx.x * 256 + t;
  const int c = labels[row];
  const int cnt = (int)min(cls_cnt[c], (unsigned)CAP);
  const float thrp = u2f_mono(nmaxu[row]) + 0.1f;  // sentinel 0 -> NaN -> hp=0
  float hp = 0.f;
  for (int j = 0; j < cnt; ++j) {
    const float p = pcache[(size_t)row * CAP + j];  // +INF diag -> compare false
    hp += (p < thrp) ? exp2f(fmaf(p, -2.885390082f, 1.442695041f)) : 0.f;
  }
  const float ap = apb[row], an = anb[row], hn = hnb[row];
  const bool valid = (ap > 0.f) && (an > 0.f);
  const float ps = (hp > 0.f) ? hp : ap;   // fallback: no hard pos -> all pos
  const float ns = (hn > 0.f) ? hn : an;   // fallback: no hard neg -> all neg
  float acc = valid ? (0.5f * log1pf(ps) + 0.02f * log1pf(ns)) : 0.f;
  float cntv = valid ? 1.f : 0.f;
#pragma unroll
  for (int o = 32; o > 0; o >>= 1) {
    acc += __shfl_down(acc, o);
    cntv += __shfl_down(cntv, o);
  }
  __shared__ float sa[4], sc[4];
  const int w = t >> 6, lane = t & 63;
  if (lane == 0) { sa[w] = acc; sc[w] = cntv; }
  __syncthreads();
  if (t == 0) {
    atomicAdd(&partial[0], sa[0] + sa[1] + sa[2] + sa[3]);
    atomicAdd(&partial[1], sc[0] + sc[1] + sc[2] + sc[3]);
    __threadfence();
    if (atomicAdd(done, 1u) == (unsigned)(NROW / 256 - 1)) {  // last block
      const float A = atomicAdd(&partial[0], 0.f);   // atomic read (coherent)
      const float C = atomicAdd(&partial[1], 0.f);
      out[0] = A / fmaxf(C, 1.f);
    }
  }
}

extern "C" void kernel_launch(void* const* d_in, const int* in_sizes, int n_in,
                              void* d_out, int out_size, void* d_ws, size_t ws_size,
                              hipStream_t stream) {
  const float* emb = (const float*)d_in[0];
  const int* labels = (const int*)d_in[1];
  float* out = (float*)d_out;

  // ws: [embh 2MB][pmin|apb 2x32KB][nmaxu|anb|hnb 3x32KB][cls_cnt 2KB|done|partial]
  //     [cls_list 128KB][pcache 2MB]
  unsigned short* embh = (unsigned short*)d_ws;
  float* pmin = (float*)((char*)d_ws + (size_t)NROW * NDIM * 2);
  float* apb = pmin + NROW;
  unsigned* nmaxu = (unsigned*)(apb + NROW);
  float* anb = (float*)(nmaxu + NROW);
  float* hnb = anb + NROW;
  unsigned* cls_cnt = (unsigned*)(hnb + NROW);
  unsigned* done = cls_cnt + NCLS;
  float* partial = (float*)(done + 1);
  int* cls_list = (int*)(partial + 2);
  float* pcache = (float*)(cls_list + NCLS * CAP);

  // tiny memset: cls_cnt + done + partial only (atomic buffers zeroed in k_convert)
  hipMemsetAsync(cls_cnt, 0, NCLS * 4 + 12, stream);

  k_convert<<<NROW * NDIM / (256 * 8), 256, 0, stream>>>(emb, embh, labels,
                                                         cls_cnt, cls_list,
                                                         nmaxu, anb, hnb);
  k_pos1<<<NCLS, 256, 0, stream>>>(emb, cls_cnt, cls_list, pmin, apb, pcache);
  dim3 grid(NROW / (CTILE * CCHUNK), NROW / RBLK);  // (32, 64)
  k_neg<<<grid, 256, 0, stream>>>(embh, labels, pmin, nmaxu, anb, hnb);
  k_final<<<NROW / 256, 256, 0, stream>>>(labels, cls_cnt, nmaxu, pcache,
                                          apb, anb, hnb, partial, done, out);
}

// Round 21
// 66.682 us; speedup vs baseline: 1.1395x; 1.1395x over previous
//
#include <hip/hip_runtime.h>
#include <hip/hip_bf16.h>

#define NROW 8192
#define NDIM 128
#define CTILE 64   // cols per tile (16KB LDS) -> L[2]=32KB/block (R19 proven config)
#define CCHUNK 8   // tiles per block -> 512 cols/block; grid (16,64)=1024 blocks
#define RBLK 128   // rows per block (4 waves x 32 rows)
#define CAP 64     // max rows per class (mean 16, P(>64) ~ 1e-20, guarded)
#define NCLS 512

typedef __attribute__((ext_vector_type(8))) short short8;
typedef __attribute__((ext_vector_type(4))) float f32x4;
typedef __attribute__((address_space(1))) const unsigned int guint;
typedef __attribute__((address_space(3))) unsigned int luint;

__device__ __forceinline__ unsigned f2u_mono(float f) {
  unsigned u = __float_as_uint(f);
  return (u & 0x80000000u) ? ~u : (u | 0x80000000u);
}
__device__ __forceinline__ float u2f_mono(unsigned u) {
  return __uint_as_float((u & 0x80000000u) ? (u ^ 0x80000000u) : ~u);
}
__device__ __forceinline__ unsigned short f2bf(float f) {  // RTN fp32->bf16
  unsigned u = __float_as_uint(f);
  u += 0x7fffu + ((u >> 16) & 1u);
  return (unsigned short)(u >> 16);
}

// ONE prologue kernel (512 blocks):
//  - zero-init nmaxu/anb/hnb (first 32 blocks' rows) + done/partial (block 0)
//  - bf16 convert of this block's slab
//  - class c = blockIdx.x: discover rows by scanning labels (32KB, L2-hot),
//    stage them to LDS, compute all pair dots (exact fp32), write
//    pmin/apb/rcnt/pcache. No cls_list, no separate prep or memset node.
__global__ __launch_bounds__(256) void k_pre(
    const float* __restrict__ emb, const int* __restrict__ labels,
    unsigned short* __restrict__ h,
    unsigned* __restrict__ nmaxu, float* __restrict__ anb, float* __restrict__ hnb,
    float* __restrict__ pmin, float* __restrict__ apb, int* __restrict__ rcnt,
    float* __restrict__ pcache, unsigned* __restrict__ done_partial) {
  __shared__ float Le[CAP][NDIM + 1];  // +1 pad: bank (j+d)%32 -> conflict-free
  __shared__ int rows_s[CAP];
  __shared__ int scnt;

  const int t = threadIdx.x;
  const int c = blockIdx.x;
  const int gid = c * 256 + t;

  // (a) zero-init for k_neg's atomics + k_final's reduction scratch
  if (gid < NROW) {
    nmaxu[gid] = 0u;   // mono sentinel: decodes to NaN -> compares false
    anb[gid] = 0.f;
    hnb[gid] = 0.f;
  }
  if (c == 0 && t < 3) done_partial[t] = 0u;  // done, partial[0..1]

  // (b) bf16 convert slab
  {
    int i = gid * 8;
    float4 f0 = *reinterpret_cast<const float4*>(emb + i);
    float4 f1 = *reinterpret_cast<const float4*>(emb + i + 4);
    ushort4 a, b;
    a.x = f2bf(f0.x); a.y = f2bf(f0.y); a.z = f2bf(f0.z); a.w = f2bf(f0.w);
    b.x = f2bf(f1.x); b.y = f2bf(f1.y); b.z = f2bf(f1.z); b.w = f2bf(f1.w);
    *reinterpret_cast<ushort4*>(h + i) = a;
    *reinterpret_cast<ushort4*>(h + i + 4) = b;
  }

  // (c) discover this class's rows: 32 strided label loads + LDS compaction
  if (t == 0) scnt = 0;
  __syncthreads();
#pragma unroll
  for (int it = 0; it < NROW / 256; ++it) {
    const int row = it * 256 + t;
    if (labels[row] == c) {
      const int idx = atomicAdd(&scnt, 1);
      if (idx < CAP) rows_s[idx] = row;
    }
  }
  __syncthreads();
  const int cnt = min(scnt, CAP);
  if (cnt == 0) return;  // class absent (block-uniform)

  // stage class rows to LDS (coalesced)
  for (int idx = t; idx < cnt * NDIM; idx += 256) {
    const int k = idx >> 7, d = idx & 127;
    Le[k][d] = emb[(size_t)rows_s[k] * NDIM + d];
  }
  __syncthreads();

  // (d) pair dots: thread (i,j)=(t>>4,t&15), 256 pairs in flight. Diagonal
  // stored +INF (min-neutral, exp(-inf)=0, hard-compare false in k_final).
  const int il = t >> 4, jl = t & 15;
  for (int ib = 0; ib < cnt; ib += 16) {
    const int i = ib + il;
    float pm = INFINITY, apv = 0.f;
    for (int jb = 0; jb < cnt; jb += 16) {
      const int j = jb + jl;
      float p = INFINITY;
      if (i < cnt && j < cnt) {
        if (i != j) {
          float s = 0.f;
#pragma unroll 8
          for (int d = 0; d < NDIM; ++d) s = fmaf(Le[i][d], Le[j][d], s);
          p = s;
        }
        pcache[(size_t)rows_s[i] * CAP + j] = p;
        if (i != j) {
          pm = fminf(pm, p);
          apv += exp2f(fmaf(p, -2.885390082f, 1.442695041f));  // exp(-2(p-.5))
        }
      }
    }
    pm = fminf(pm, __shfl_xor(pm, 1)); pm = fminf(pm, __shfl_xor(pm, 2));
    pm = fminf(pm, __shfl_xor(pm, 4)); pm = fminf(pm, __shfl_xor(pm, 8));
    apv += __shfl_xor(apv, 1); apv += __shfl_xor(apv, 2);
    apv += __shfl_xor(apv, 4); apv += __shfl_xor(apv, 8);
    if (jl == 0 && i < cnt) {
      pmin[rows_s[i]] = pm;   // +INF if class has a single row
      apb[rows_s[i]] = apv;
      rcnt[rows_s[i]] = cnt;
    }
  }
}

// DMA one 64x128 bf16 col-tile into LDS. Dest LINEAR (global_load_lds writes
// wave-uniform base + lane*16); XOR swizzle applied to the GLOBAL source chunk.
__device__ __forceinline__ void stage_tile(const unsigned short* __restrict__ eh,
                                           int colBase, int t,
                                           unsigned short* __restrict__ Lbuf) {
#pragma unroll
  for (int it = 0; it < 4; ++it) {
    const int idx = it * 256 + t;
    const int r = idx >> 4;
    const int c = idx & 15;
    const int q = c ^ (r & 15);
    const unsigned short* src = eh + (size_t)(colBase + r) * NDIM + q * 8;
    unsigned short* dst = Lbuf + r * NDIM + c * 8;
    __builtin_amdgcn_global_load_lds((guint*)src, (luint*)dst, 16, 0, 0);
  }
}

// kk=0 uses a hoisted zero f32x4 as the C operand -> no per-tile acc zeroing.
__device__ __forceinline__ void mfma_from_lds(const unsigned short* __restrict__ Lbuf,
                                              const short8 (&bv)[4][2],
                                              const f32x4& Z,
                                              int g, int l15,
                                              f32x4 (&acc)[4][2]) {
#pragma unroll
  for (int kk = 0; kk < 4; ++kk) {
    short8 av[4];
#pragma unroll
    for (int m = 0; m < 4; ++m) {
      const int R = m * 16 + l15;
      const int pc = (kk * 4 + g) ^ l15;
      av[m] = *reinterpret_cast<const short8*>(Lbuf + R * NDIM + pc * 8);
    }
#pragma unroll
    for (int m = 0; m < 4; ++m)
#pragma unroll
      for (int n = 0; n < 2; ++n)
        acc[m][n] = __builtin_amdgcn_mfma_f32_16x16x32_bf16(
            av[m], bv[kk][n], (kk == 0) ? Z : acc[m][n], 0, 0, 0);
  }
}

// Negatives pass (R19-proven, 46us): the ONE full GEMM. x-trick epilogue:
// x = eq ? -inf : s feeds nmax (neutral), exp (0), and hn compare (false).
__global__ __launch_bounds__(256, 3) void k_neg(
    const unsigned short* __restrict__ eh, const int* __restrict__ labels,
    const float* __restrict__ pmin, unsigned* __restrict__ nmaxu,
    float* __restrict__ anb, float* __restrict__ hnb) {
  __shared__ unsigned short L[2][CTILE * NDIM];  // 2 x 16KB

  const int t = threadIdx.x;
  const int lane = t & 63;
  const int wid = t >> 6;   // 4 waves x 32 rows
  const int g = lane >> 4;
  const int l15 = lane & 15;
  const int rowBase = blockIdx.y * RBLK;
  const int col0 = blockIdx.x * CCHUNK * CTILE;

  stage_tile(eh, col0, t, L[0]);  // prologue DMA for tile 0

  short8 bv[4][2];
  int lr[2];
  float thrn[2];
#pragma unroll
  for (int n = 0; n < 2; ++n) {
    const int grow = rowBase + wid * 32 + n * 16 + l15;
    lr[n] = labels[grow];
    thrn[n] = pmin[grow] - 0.1f;  // +INF if no positives -> x>thrn false -> hn=0
#pragma unroll
    for (int kk = 0; kk < 4; ++kk)
      bv[kk][n] = *reinterpret_cast<const short8*>(eh + (size_t)grow * NDIM + kk * 32 + g * 8);
  }

  float nmaxA[2] = {-INFINITY, -INFINITY};
  float anA[2] = {0.f, 0.f}, hnA[2] = {0.f, 0.f};
  const f32x4 Z = {0.f, 0.f, 0.f, 0.f};

  asm volatile("s_waitcnt vmcnt(0)");
  __syncthreads();

  f32x4 acc[4][2];
  int cur = 0;
  for (int tt = 0; tt < CCHUNK; ++tt) {
    const int colBase = col0 + tt * CTILE;
    if (tt + 1 < CCHUNK) stage_tile(eh, colBase + CTILE, t, L[cur ^ 1]);  // DMA next
    int4 lcv[4];  // issued before MFMA so L2 latency hides under it
#pragma unroll
    for (int m = 0; m < 4; ++m)
      lcv[m] = *reinterpret_cast<const int4*>(labels + colBase + m * 16 + g * 4);
    mfma_from_lds(L[cur], bv, Z, g, l15, acc);
#pragma unroll
    for (int n = 0; n < 2; ++n) {
#pragma unroll
      for (int m = 0; m < 4; ++m) {
#pragma unroll
        for (int r = 0; r < 4; ++r) {
          const float s = acc[m][n][r];
          const int lc = (r == 0) ? lcv[m].x : (r == 1) ? lcv[m].y
                        : (r == 2) ? lcv[m].z : lcv[m].w;
          const float x = (lr[n] == lc) ? -INFINITY : s;   // excl. pos + diag
          nmaxA[n] = fmaxf(nmaxA[n], x);
          const float e = exp2f(fmaf(x, 72.13475205f, -36.06737602f));  // exp(50(x-.5))
          anA[n] += e;                                      // 0 when excluded
          hnA[n] += (x > thrn[n]) ? e : 0.f;                // false when excluded
        }
      }
    }
    asm volatile("s_waitcnt vmcnt(0)");  // next-tile DMA landed (covered by compute)
    __syncthreads();
    cur ^= 1;
  }

  // block-end combine: butterfly across the 4 g-groups, then one atomic per lane
#pragma unroll
  for (int n = 0; n < 2; ++n) {
    const int grow = rowBase + wid * 32 + n * 16 + l15;
    float nm = nmaxA[n], a0 = anA[n], a1 = hnA[n];
    nm = fmaxf(nm, __shfl_xor(nm, 16)); nm = fmaxf(nm, __shfl_xor(nm, 32));
    a0 += __shfl_xor(a0, 16); a0 += __shfl_xor(a0, 32);
    a1 += __shfl_xor(a1, 16); a1 += __shfl_xor(a1, 32);
    if (g == 0 && nm > -INFINITY) atomicMax(&nmaxu[grow], f2u_mono(nm));
    if (g == 1 && a0 > 0.f) atomicAdd(&anb[grow], a0);
    if (g == 2 && a1 > 0.f) atomicAdd(&hnb[grow], a1);
  }
}

// Fused hard-pos + final reduction: 32 blocks, thread per row. hp from cached
// pos dots; block partials via atomicAdd; last-done block writes the mean.
__global__ __launch_bounds__(256) void k_final(
    const int* __restrict__ rcnt, const unsigned* __restrict__ nmaxu,
    const float* __restrict__ pcache, const float* __restrict__ apb,
    const float* __restrict__ anb, const float* __restrict__ hnb,
    unsigned* __restrict__ done_partial, float* __restrict__ out) {
  unsigned* done = done_partial;
  float* partial = (float*)(done_partial + 1);
  const int t = threadIdx.x;
  const int row = blockIdx.x * 256 + t;
  const int cnt = min(rcnt[row], CAP);
  const float thrp = u2f_mono(nmaxu[row]) + 0.1f;  // sentinel 0 -> NaN -> hp=0
  float hp = 0.f;
  for (int j = 0; j < cnt; ++j) {
    const float p = pcache[(size_t)row * CAP + j];  // +INF diag -> compare false
    hp += (p < thrp) ? exp2f(fmaf(p, -2.885390082f, 1.442695041f)) : 0.f;
  }
  const float ap = apb[row], an = anb[row], hn = hnb[row];
  const bool valid = (ap > 0.f) && (an > 0.f);
  const float ps = (hp > 0.f) ? hp : ap;   // fallback: no hard pos -> all pos
  const float ns = (hn > 0.f) ? hn : an;   // fallback: no hard neg -> all neg
  float acc = valid ? (0.5f * log1pf(ps) + 0.02f * log1pf(ns)) : 0.f;
  float cntv = valid ? 1.f : 0.f;
#pragma unroll
  for (int o = 32; o > 0; o >>= 1) {
    acc += __shfl_down(acc, o);
    cntv += __shfl_down(cntv, o);
  }
  __shared__ float sa[4], sc[4];
  const int w = t >> 6, lane = t & 63;
  if (lane == 0) { sa[w] = acc; sc[w] = cntv; }
  __syncthreads();
  if (t == 0) {
    atomicAdd(&partial[0], sa[0] + sa[1] + sa[2] + sa[3]);
    atomicAdd(&partial[1], sc[0] + sc[1] + sc[2] + sc[3]);
    __threadfence();
    if (atomicAdd(done, 1u) == (unsigned)(NROW / 256 - 1)) {  // last block
      const float A = atomicAdd(&partial[0], 0.f);   // atomic read (coherent)
      const float C = atomicAdd(&partial[1], 0.f);
      out[0] = A / fmaxf(C, 1.f);
    }
  }
}

extern "C" void kernel_launch(void* const* d_in, const int* in_sizes, int n_in,
                              void* d_out, int out_size, void* d_ws, size_t ws_size,
                              hipStream_t stream) {
  const float* emb = (const float*)d_in[0];
  const int* labels = (const int*)d_in[1];
  float* out = (float*)d_out;

  // ws: [embh 2MB][pmin|apb|nmaxu|anb|hnb|rcnt 6x32KB][done+partial 16B][pcache 2MB]
  unsigned short* embh = (unsigned short*)d_ws;
  float* pmin = (float*)((char*)d_ws + (size_t)NROW * NDIM * 2);
  float* apb = pmin + NROW;
  unsigned* nmaxu = (unsigned*)(apb + NROW);
  float* anb = (float*)(nmaxu + NROW);
  float* hnb = anb + NROW;
  int* rcnt = (int*)(hnb + NROW);
  unsigned* done_partial = (unsigned*)(rcnt + NROW);
  float* pcache = (float*)(done_partial + 4);

  // 3-node graph: pre (init+convert+positives), neg (the GEMM), final
  k_pre<<<NCLS, 256, 0, stream>>>(emb, labels, embh, nmaxu, anb, hnb,
                                  pmin, apb, rcnt, pcache, done_partial);
  dim3 grid(NROW / (CTILE * CCHUNK), NROW / RBLK);  // (16, 64)
  k_neg<<<grid, 256, 0, stream>>>(embh, labels, pmin, nmaxu, anb, hnb);
  k_final<<<NROW / 256, 256, 0, stream>>>(rcnt, nmaxu, pcache,
                                          apb, anb, hnb, done_partial, out);
}